// Round 9
// baseline (299.167 us; speedup 1.0000x reference)
//
#include <hip/hip_runtime.h>
#include <hip/hip_bf16.h>
#include <hip/hip_fp16.h>
#include <float.h>

#define F 128          // hidden = H*C
#define HEADS 4
#define CPH 32

using f16x8 = __attribute__((ext_vector_type(8))) _Float16;
using f32x4 = __attribute__((ext_vector_type(4))) float;

// ---------------- CSR build ----------------

__global__ void count_deg_kernel(const int* __restrict__ dst, int* __restrict__ deg, int E) {
    int i = blockIdx.x * blockDim.x + threadIdx.x;
    if (i < E) atomicAdd(&deg[dst[i]], 1);
}

__global__ __launch_bounds__(1024) void scan1_kernel(const int* __restrict__ deg,
                                                     int* __restrict__ excl,
                                                     int* __restrict__ bsums, int n) {
    __shared__ int tmp[1024];
    int i = blockIdx.x * 1024 + threadIdx.x;
    int v = (i < n) ? deg[i] : 0;
    tmp[threadIdx.x] = v;
    __syncthreads();
    for (int o = 1; o < 1024; o <<= 1) {
        int a = (threadIdx.x >= o) ? tmp[threadIdx.x - o] : 0;
        __syncthreads();
        tmp[threadIdx.x] += a;
        __syncthreads();
    }
    if (i < n) excl[i] = tmp[threadIdx.x] - v;
    if (threadIdx.x == 1023) bsums[blockIdx.x] = tmp[1023];
}

__global__ __launch_bounds__(1024) void scan2_kernel(int* __restrict__ bsums, int nb) {
    __shared__ int tmp[1024];
    int v = (threadIdx.x < nb) ? bsums[threadIdx.x] : 0;
    tmp[threadIdx.x] = v;
    __syncthreads();
    for (int o = 1; o < 1024; o <<= 1) {
        int a = (threadIdx.x >= o) ? tmp[threadIdx.x - o] : 0;
        __syncthreads();
        tmp[threadIdx.x] += a;
        __syncthreads();
    }
    if (threadIdx.x < nb) bsums[threadIdx.x] = tmp[threadIdx.x] - v;  // exclusive
}

__global__ void scan3_kernel(const int* __restrict__ excl, const int* __restrict__ bsums,
                             int* __restrict__ row_ptr, int* __restrict__ cursor,
                             int n, int E) {
    int i = blockIdx.x * 256 + threadIdx.x;
    if (i < n) {
        int v = excl[i] + bsums[i >> 10];
        row_ptr[i] = v;
        cursor[i] = v;
    }
    if (i == n) row_ptr[n] = E;
}

__global__ void scatter_kernel(const int* __restrict__ src, const int* __restrict__ dst,
                               int* __restrict__ cursor, int* __restrict__ srcs, int E) {
    int i = blockIdx.x * blockDim.x + threadIdx.x;
    if (i < E) {
        int pos = atomicAdd(&cursor[dst[i]], 1);
        srcs[pos] = src[i];
    }
}

// ---------------- converts ----------------

// W[k][n] fp32 -> Wt[n][k] fp16, 4 matrices. 256 blocks (64/matrix) x 256 thr.
__global__ void convw_kernel(const float* __restrict__ W0, const float* __restrict__ W1,
                             const float* __restrict__ W2, const float* __restrict__ W3,
                             _Float16* __restrict__ T0, _Float16* __restrict__ T1,
                             _Float16* __restrict__ T2, _Float16* __restrict__ T3) {
    int m   = blockIdx.x >> 6;
    int tid = (blockIdx.x & 63) * 256 + threadIdx.x;   // 0..16383 = n*128+k
    int n = tid >> 7, k = tid & 127;
    const float* W = m == 0 ? W0 : m == 1 ? W1 : m == 2 ? W2 : W3;
    _Float16*    T = m == 0 ? T0 : m == 1 ? T1 : m == 2 ? T2 : T3;
    T[tid] = (_Float16)W[k * F + n];
}

// ---------------- dual MFMA GEMM, B-in-VGPR ----------------
// 512 thr = 8 waves: wave (wr = wid&3, m = wid>>2). Wave handles 16 rows x 128 cols
// of ONE matrix (m=0: Wl -> xl fp16; m=1: Wr -> xr fp32). B = 32 f16x8 frags loaded
// ONCE into 128 VGPRs (the R8 kernel re-loaded them from L2 inside the MFMA loop ->
// ~200cyc exposed latency each iter). VGPR ~200 < 256 cap of (512,2) -> no spill.
// A/B use the same k-slot map (k = t*32 + g*8 + j); C/D layout col=lane&15,
// row=(lane>>4)*4+reg (verified). A rows clamped, C stores guarded for N tail.

template<int A_FP32>
__global__ __launch_bounds__(512, 2) void mfma_dual_gemm_kernel(
    const void* __restrict__ Xin,
    const _Float16* __restrict__ Wlt, const float* __restrict__ bl,
    const _Float16* __restrict__ Wrt, const float* __restrict__ br,
    _Float16* __restrict__ xl, float* __restrict__ xr, int N)
{
    const int wid  = threadIdx.x >> 6;
    const int lane = threadIdx.x & 63;
    const int wr   = wid & 3;
    const int m    = wid >> 2;             // 0: L, 1: R
    const int row0 = blockIdx.x * 64 + wr * 16;
    const int arow = lane & 15;
    const int g    = lane >> 4;            // 0..3

    const _Float16* Wt = m ? Wrt : Wlt;

    // B fragments: entire 128x128 W^T for this matrix, once.
    f16x8 bf[32];
    #pragma unroll
    for (int nt = 0; nt < 8; ++nt)
        #pragma unroll
        for (int t = 0; t < 4; ++t)
            bf[nt * 4 + t] = *(const f16x8*)(Wt + (size_t)(nt * 16 + arow) * F + t * 32 + g * 8);

    // A fragments (convert fp32 inline for layer 1)
    int xrow = row0 + arow;
    if (xrow >= N) xrow = N - 1;           // clamp (C stores guarded)
    f16x8 af[4];
    if (A_FP32) {
        const float* xp = (const float*)Xin + (size_t)xrow * F + g * 8;
        #pragma unroll
        for (int t = 0; t < 4; ++t) {
            float4 lo = *(const float4*)(xp + t * 32);
            float4 hi = *(const float4*)(xp + t * 32 + 4);
            f16x8 a;
            a[0] = (_Float16)lo.x; a[1] = (_Float16)lo.y; a[2] = (_Float16)lo.z; a[3] = (_Float16)lo.w;
            a[4] = (_Float16)hi.x; a[5] = (_Float16)hi.y; a[6] = (_Float16)hi.z; a[7] = (_Float16)hi.w;
            af[t] = a;
        }
    } else {
        const _Float16* xp = (const _Float16*)Xin + (size_t)xrow * F + g * 8;
        #pragma unroll
        for (int t = 0; t < 4; ++t)
            af[t] = *(const f16x8*)(xp + t * 32);
    }

    f32x4 acc[8];
    #pragma unroll
    for (int nt = 0; nt < 8; ++nt) acc[nt] = (f32x4){0.f, 0.f, 0.f, 0.f};

    #pragma unroll
    for (int t = 0; t < 4; ++t)
        #pragma unroll
        for (int nt = 0; nt < 8; ++nt)
            acc[nt] = __builtin_amdgcn_mfma_f32_16x16x32_f16(af[t], bf[nt * 4 + t], acc[nt], 0, 0, 0);

    const float* bias = m ? br : bl;
    #pragma unroll
    for (int nt = 0; nt < 8; ++nt) {
        int ccol = nt * 16 + (lane & 15);
        float bv = bias[ccol];
        #pragma unroll
        for (int r2 = 0; r2 < 4; ++r2) {
            int crow = row0 + (lane >> 4) * 4 + r2;
            if (crow < N) {
                float v = acc[nt][r2] + bv;
                if (m == 0) xl[(size_t)crow * F + ccol] = (_Float16)v;
                else        xr[(size_t)crow * F + ccol] = v;
            }
        }
    }
}

// ---------------- fused edge phase (R7-proven, fp16 xl gather) ----------------
// 1 wave per node; thread t owns channels (2t, 2t+1); head group = 16 lanes.
// Plain exp (logits O(5), exp-safe in fp32). 4 independent chains in flight.
// out_half: layer-1 writes fp16 h (feeds layer-2 MFMA GEMM directly).

__device__ __forceinline__ float edge_logit(float2 v, float2 xr_t, float2 a_t) {
    float e0 = v.x + xr_t.x; e0 = e0 >= 0.f ? e0 : 0.2f * e0;
    float e1 = v.y + xr_t.y; e1 = e1 >= 0.f ? e1 : 0.2f * e1;
    float p = e0 * a_t.x + e1 * a_t.y;
    p += __shfl_xor(p, 8);
    p += __shfl_xor(p, 4);
    p += __shfl_xor(p, 2);
    p += __shfl_xor(p, 1);
    return p;
}

__global__ __launch_bounds__(256) void gat_edge_kernel(
    const __half2* __restrict__ xlh, const float2* __restrict__ xr2,
    const int* __restrict__ srcs, const int* __restrict__ row_ptr,
    const float2* __restrict__ att2, const float2* __restrict__ bias2,
    float2* __restrict__ outf, __half2* __restrict__ outh,
    int N, int do_relu, int out_half)
{
    int node = blockIdx.x * 4 + threadIdx.y;
    int t = threadIdx.x;                       // 0..63
    if (node >= N) return;
    float2 xr_t = xr2[(size_t)node * 64 + t];
    float2 a_t  = att2[t];
    int beg = row_ptr[node], end = row_ptr[node + 1];
    float s = 0.f;
    float ox = 0.f, oy = 0.f;
    int i = beg;
    for (; i + 4 <= end; i += 4) {
        int sn0 = srcs[i], sn1 = srcs[i + 1], sn2 = srcs[i + 2], sn3 = srcs[i + 3];
        float2 v0 = __half22float2(xlh[(size_t)sn0 * 64 + t]);
        float2 v1 = __half22float2(xlh[(size_t)sn1 * 64 + t]);
        float2 v2 = __half22float2(xlh[(size_t)sn2 * 64 + t]);
        float2 v3 = __half22float2(xlh[(size_t)sn3 * 64 + t]);
        float p0 = edge_logit(v0, xr_t, a_t);
        float p1 = edge_logit(v1, xr_t, a_t);
        float p2 = edge_logit(v2, xr_t, a_t);
        float p3 = edge_logit(v3, xr_t, a_t);
        float w0 = __expf(p0), w1 = __expf(p1), w2 = __expf(p2), w3 = __expf(p3);
        s += (w0 + w1) + (w2 + w3);
        ox = fmaf(w0, v0.x, ox); oy = fmaf(w0, v0.y, oy);
        ox = fmaf(w1, v1.x, ox); oy = fmaf(w1, v1.y, oy);
        ox = fmaf(w2, v2.x, ox); oy = fmaf(w2, v2.y, oy);
        ox = fmaf(w3, v3.x, ox); oy = fmaf(w3, v3.y, oy);
    }
    for (; i < end; ++i) {
        int sn = srcs[i];
        float2 v = __half22float2(xlh[(size_t)sn * 64 + t]);
        float p = edge_logit(v, xr_t, a_t);
        float w = __expf(p);
        s += w;
        ox = fmaf(w, v.x, ox); oy = fmaf(w, v.y, oy);
    }
    float inv = 1.f / (s + 1e-16f);
    float2 bi = bias2[t];
    float rx = ox * inv + bi.x;
    float ry = oy * inv + bi.y;
    if (do_relu) { rx = fmaxf(rx, 0.f); ry = fmaxf(ry, 0.f); }
    if (out_half) {
        outh[(size_t)node * 64 + t] = __floats2half2_rn(rx, ry);
    } else {
        float2 rr; rr.x = rx; rr.y = ry;
        outf[(size_t)node * 64 + t] = rr;
    }
}

// ---------------- launch ----------------

extern "C" void kernel_launch(void* const* d_in, const int* in_sizes, int n_in,
                              void* d_out, int out_size, void* d_ws, size_t ws_size,
                              hipStream_t stream)
{
    const float* x    = (const float*)d_in[0];
    const int*   ei   = (const int*)d_in[1];
    const float* Wl1  = (const float*)d_in[2];
    const float* Wr1  = (const float*)d_in[3];
    const float* Wl2  = (const float*)d_in[4];
    const float* Wr2  = (const float*)d_in[5];
    const float* bl1  = (const float*)d_in[6];
    const float* br1  = (const float*)d_in[7];
    const float* bl2  = (const float*)d_in[8];
    const float* br2  = (const float*)d_in[9];
    const float* att1 = (const float*)d_in[10];
    const float* att2 = (const float*)d_in[11];
    const float* b1   = (const float*)d_in[12];
    const float* b2   = (const float*)d_in[13];

    const int N = in_sizes[0] / F;
    const int E = in_sizes[1] / 2;
    const int* src = ei;
    const int* dst = ei + E;

    char* ws = (char*)d_ws;
    size_t off = 0;
    auto alloc = [&](size_t bytes) -> void* {
        void* p = ws + off;
        off = (off + bytes + 255) & ~(size_t)255;
        return p;
    };
    _Float16* hh   = (_Float16*)alloc((size_t)N * F * sizeof(_Float16));  // fp16 h (layer2 in)
    _Float16* xlh  = (_Float16*)alloc((size_t)N * F * sizeof(_Float16));  // fp16 xl
    float*    xr   = (float*)alloc((size_t)N * F * sizeof(float));        // fp32 xr
    _Float16* Wt1l = (_Float16*)alloc((size_t)F * F * sizeof(_Float16));
    _Float16* Wt1r = (_Float16*)alloc((size_t)F * F * sizeof(_Float16));
    _Float16* Wt2l = (_Float16*)alloc((size_t)F * F * sizeof(_Float16));
    _Float16* Wt2r = (_Float16*)alloc((size_t)F * F * sizeof(_Float16));
    int* row_ptr   = (int*)alloc((size_t)(N + 1) * sizeof(int));
    int* deg       = (int*)alloc((size_t)N * sizeof(int));
    int* excl      = (int*)alloc((size_t)N * sizeof(int));
    int* bsums     = (int*)alloc((size_t)1024 * sizeof(int));
    int* cursor    = (int*)alloc((size_t)N * sizeof(int));
    int* srcs      = (int*)alloc((size_t)E * sizeof(int));

    // CSR build
    hipMemsetAsync(deg, 0, (size_t)N * sizeof(int), stream);
    count_deg_kernel<<<(E + 255) / 256, 256, 0, stream>>>(dst, deg, E);
    const int nchunks = (N + 1023) / 1024;
    scan1_kernel<<<nchunks, 1024, 0, stream>>>(deg, excl, bsums, N);
    scan2_kernel<<<1, 1024, 0, stream>>>(bsums, nchunks);
    scan3_kernel<<<(N + 256) / 256, 256, 0, stream>>>(excl, bsums, row_ptr, cursor, N, E);
    scatter_kernel<<<(E + 255) / 256, 256, 0, stream>>>(src, dst, cursor, srcs, E);

    // weight transpose+convert (one tiny dispatch)
    convw_kernel<<<256, 256, 0, stream>>>(Wl1, Wr1, Wl2, Wr2, Wt1l, Wt1r, Wt2l, Wt2r);

    const int gemm_blocks = (N + 63) / 64;
    dim3 eb(64, 4);
    const int edge_blocks = (N + 3) / 4;

    // layer 1 (A fp32, converted inline)
    mfma_dual_gemm_kernel<1><<<gemm_blocks, 512, 0, stream>>>(
        x, Wt1l, bl1, Wt1r, br1, xlh, xr, N);
    gat_edge_kernel<<<edge_blocks, eb, 0, stream>>>(
        (const __half2*)xlh, (const float2*)xr, srcs, row_ptr,
        (const float2*)att1, (const float2*)b1,
        nullptr, (__half2*)hh, N, 1, 1);

    // layer 2 (A fp16 from edge layer 1)
    mfma_dual_gemm_kernel<0><<<gemm_blocks, 512, 0, stream>>>(
        hh, Wt2l, bl2, Wt2r, br2, xlh, xr, N);
    gat_edge_kernel<<<edge_blocks, eb, 0, stream>>>(
        (const __half2*)xlh, (const float2*)xr, srcs, row_ptr,
        (const float2*)att2, (const float2*)b2,
        (float2*)d_out, nullptr, N, 0, 0);
}